// Round 2
// baseline (446.337 us; speedup 1.0000x reference)
//
#include <hip/hip_runtime.h>

typedef unsigned short u16;
typedef unsigned int u32;
typedef short bf16x8 __attribute__((ext_vector_type(8)));
typedef float f32x4 __attribute__((ext_vector_type(4)));

constexpr int Bb = 2, Cc = 1024, Tt = 2048, Hh = 16, Dd = 64;

__device__ __forceinline__ u16 f2bf(float f) {
    union { float f; u32 i; } c; c.f = f;
    u32 u = c.i;
    u32 r = (u + 0x7FFFu + ((u >> 16) & 1u)) >> 16;
    return (u16)r;
}

// ---------------- fp32 -> bf16 elementwise (weights) ----------------
__global__ __launch_bounds__(256) void cvt_bf16(const float* __restrict__ in,
                                                u16* __restrict__ out, int n) {
    int i = (blockIdx.x * 256 + threadIdx.x) * 4;
    if (i + 3 < n) {
        float4 v = *(const float4*)(in + i);
        out[i + 0] = f2bf(v.x);
        out[i + 1] = f2bf(v.y);
        out[i + 2] = f2bf(v.z);
        out[i + 3] = f2bf(v.w);
    }
}

// ---------------- x transpose+convert: fp32 [b][c][t] -> bf16 [b][t][c] ----------------
__global__ __launch_bounds__(256) void transpose_x(const float* __restrict__ x,
                                                   u16* __restrict__ xT) {
    __shared__ u16 tile[32][33];
    int b = blockIdx.z;
    int t0 = blockIdx.x * 32, c0 = blockIdx.y * 32;
    int tx = threadIdx.x, ty = threadIdx.y;
    const float* xb = x + (size_t)b * Cc * Tt;
    u16* xTb = xT + (size_t)b * Tt * Cc;
#pragma unroll
    for (int i = 0; i < 4; i++) {
        int r = ty + i * 8;
        tile[r][tx] = f2bf(xb[(size_t)(c0 + r) * Tt + t0 + tx]);
    }
    __syncthreads();
#pragma unroll
    for (int i = 0; i < 4; i++) {
        int r = ty + i * 8;
        xTb[(size_t)(t0 + r) * Cc + c0 + tx] = tile[tx][r];
    }
}

// ---------------- GEMM: D[m,n] = sum_k A[m,k]*Bt[n,k] + bias[n] ----------------
// A: per-batch [M=2048][K=1024] row-major bf16 (k contiguous)
// Bt: [N=1024][K=1024] row-major bf16  == W[o][c] converted
// mode 0/1: out = q/k buf bf16 [b][h][t][d]
// mode 2  : out = vT buf  bf16 [b][h][d][t]
// mode 3  : out = d_out  fp32 [b][o][t], val = (acc+bias)*mask[b][t]
__global__ __launch_bounds__(256) void gemm_bt(const u16* __restrict__ A,
                                               const u16* __restrict__ Bt,
                                               const float* __restrict__ bias,
                                               const int* __restrict__ mask,
                                               void* __restrict__ outv, int mode) {
    constexpr int M = Tt, K = Cc;
    __shared__ u16 Alds[64][40];
    __shared__ u16 Blds[64][40];
    int b = blockIdx.z;
    int n0 = blockIdx.x * 64, m0 = blockIdx.y * 64;
    int tid = threadIdx.x;
    int lane = tid & 63, wave = tid >> 6;
    int quad = lane >> 4, id15 = lane & 15;
    int wm = (wave & 1) * 32, wn = (wave >> 1) * 32;
    const u16* Ab = A + (size_t)b * M * K;
    int srow = tid >> 2, scg = tid & 3;

    f32x4 acc[2][2] = {};

    for (int k0 = 0; k0 < K; k0 += 32) {
        __syncthreads();
        uint4 av = *(const uint4*)(Ab + (size_t)(m0 + srow) * K + k0 + scg * 8);
        uint4 bv = *(const uint4*)(Bt + (size_t)(n0 + srow) * K + k0 + scg * 8);
        *(uint4*)(&Alds[srow][scg * 8]) = av;
        *(uint4*)(&Blds[srow][scg * 8]) = bv;
        __syncthreads();
        bf16x8 af[2], bff[2];
#pragma unroll
        for (int mi = 0; mi < 2; mi++)
            af[mi] = *(const bf16x8*)(&Alds[wm + mi * 16 + id15][quad * 8]);
#pragma unroll
        for (int ni = 0; ni < 2; ni++)
            bff[ni] = *(const bf16x8*)(&Blds[wn + ni * 16 + id15][quad * 8]);
#pragma unroll
        for (int mi = 0; mi < 2; mi++)
#pragma unroll
            for (int ni = 0; ni < 2; ni++)
                acc[mi][ni] = __builtin_amdgcn_mfma_f32_16x16x32_bf16(
                    af[mi], bff[ni], acc[mi][ni], 0, 0, 0);
    }

#pragma unroll
    for (int mi = 0; mi < 2; mi++) {
#pragma unroll
        for (int ni = 0; ni < 2; ni++) {
            int n = n0 + wn + ni * 16 + id15;
            float bvv = bias[n];
#pragma unroll
            for (int r = 0; r < 4; r++) {
                int m = m0 + wm + mi * 16 + quad * 4 + r;
                float v = acc[mi][ni][r] + bvv;
                if (mode <= 1) {
                    int h = n >> 6, d = n & 63;
                    ((u16*)outv)[(((size_t)b * Hh + h) * Tt + m) * Dd + d] = f2bf(v);
                } else if (mode == 2) {
                    int h = n >> 6, d = n & 63;
                    ((u16*)outv)[(((size_t)b * Hh + h) * Dd + d) * Tt + m] = f2bf(v);
                } else {
                    float mm = mask[b * Tt + m] ? 1.0f : 0.0f;
                    ((float*)outv)[((size_t)b * Cc + n) * Tt + m] = v * mm;
                }
            }
        }
    }
}

// ---------------- flash attention: per (b,h), 64 q-rows/block, 32-key chunks ----------------
// q,k: [b][h][t][d] bf16 ; vT: [b][h][d][t] bf16 ; o_buf: [b][t][h*64+d] bf16
__global__ __launch_bounds__(256) void attn(const u16* __restrict__ q,
                                            const u16* __restrict__ kk,
                                            const u16* __restrict__ vT,
                                            const int* __restrict__ mask,
                                            u16* __restrict__ o_buf) {
    __shared__ u16 Plds[4][16][40];
    int bh = blockIdx.y;
    int b = bh >> 4;
    int h = bh & 15;
    int t0 = blockIdx.x * 64;
    int tid = threadIdx.x;
    int lane = tid & 63, wave = tid >> 6;
    int quad = lane >> 4, id15 = lane & 15;
    int qrow = t0 + wave * 16;
    const u16* qb = q + (size_t)bh * Tt * Dd;
    const u16* kb = kk + (size_t)bh * Tt * Dd;
    const u16* vb = vT + (size_t)bh * Dd * Tt;

    bf16x8 aq[2];
#pragma unroll
    for (int hf = 0; hf < 2; hf++)
        aq[hf] = *(const bf16x8*)(qb + (size_t)(qrow + id15) * Dd + hf * 32 + quad * 8);

    float m_s[4], l_s[4];
    f32x4 accO[4] = {};
#pragma unroll
    for (int r = 0; r < 4; r++) { m_s[r] = -1e30f; l_s[r] = 0.0f; }

    for (int j0 = 0; j0 < Tt; j0 += 32) {
        f32x4 s[2] = {};
#pragma unroll
        for (int nh = 0; nh < 2; nh++) {
#pragma unroll
            for (int hf = 0; hf < 2; hf++) {
                bf16x8 bk = *(const bf16x8*)(kb + (size_t)(j0 + nh * 16 + id15) * Dd +
                                             hf * 32 + quad * 8);
                s[nh] = __builtin_amdgcn_mfma_f32_16x16x32_bf16(aq[hf], bk, s[nh], 0, 0, 0);
            }
        }
        // scale + key-mask (finite sentinel; online-softmax self-corrects)
#pragma unroll
        for (int nh = 0; nh < 2; nh++) {
            int key = j0 + nh * 16 + id15;
            bool mv = mask[b * Tt + key] != 0;
#pragma unroll
            for (int r = 0; r < 4; r++)
                s[nh][r] = mv ? s[nh][r] * 0.125f : -1e30f;
        }
        // row max across the 16 lanes of each quad (row = quad*4+r)
        float mx[4];
#pragma unroll
        for (int r = 0; r < 4; r++) mx[r] = fmaxf(s[0][r], s[1][r]);
#pragma unroll
        for (int off = 1; off <= 8; off <<= 1)
#pragma unroll
            for (int r = 0; r < 4; r++) mx[r] = fmaxf(mx[r], __shfl_xor(mx[r], off));
        float alpha[4];
#pragma unroll
        for (int r = 0; r < 4; r++) {
            float mn = fmaxf(m_s[r], mx[r]);
            alpha[r] = __expf(m_s[r] - mn);
            m_s[r] = mn;
        }
#pragma unroll
        for (int nh = 0; nh < 2; nh++)
#pragma unroll
            for (int r = 0; r < 4; r++) s[nh][r] = __expf(s[nh][r] - m_s[r]);
        float rs[4];
#pragma unroll
        for (int r = 0; r < 4; r++) rs[r] = s[0][r] + s[1][r];
#pragma unroll
        for (int off = 1; off <= 8; off <<= 1)
#pragma unroll
            for (int r = 0; r < 4; r++) rs[r] += __shfl_xor(rs[r], off);
#pragma unroll
        for (int r = 0; r < 4; r++) l_s[r] = l_s[r] * alpha[r] + rs[r];
#pragma unroll
        for (int nt = 0; nt < 4; nt++)
#pragma unroll
            for (int r = 0; r < 4; r++) accO[nt][r] *= alpha[r];

        __syncthreads();  // protect Plds reuse across chunks
#pragma unroll
        for (int r = 0; r < 4; r++) {
            Plds[wave][quad * 4 + r][id15] = f2bf(s[0][r]);
            Plds[wave][quad * 4 + r][16 + id15] = f2bf(s[1][r]);
        }
        __syncthreads();
        bf16x8 ap = *(const bf16x8*)(&Plds[wave][id15][quad * 8]);
#pragma unroll
        for (int nt = 0; nt < 4; nt++) {
            bf16x8 bv = *(const bf16x8*)(vb + (size_t)(nt * 16 + id15) * Tt + j0 + quad * 8);
            accO[nt] = __builtin_amdgcn_mfma_f32_16x16x32_bf16(ap, bv, accO[nt], 0, 0, 0);
        }
    }

    float inv[4];
#pragma unroll
    for (int r = 0; r < 4; r++) inv[r] = 1.0f / l_s[r];
#pragma unroll
    for (int nt = 0; nt < 4; nt++)
#pragma unroll
        for (int r = 0; r < 4; r++) {
            int t = qrow + quad * 4 + r;
            o_buf[((size_t)b * Tt + t) * Cc + h * Dd + nt * 16 + id15] =
                f2bf(accO[nt][r] * inv[r]);
        }
}

// ---------------- mask tail of d_out (fp32 0/1) ----------------
__global__ void mask_out_k(const int* __restrict__ mask, float* __restrict__ out) {
    int i = blockIdx.x * 256 + threadIdx.x;
    if (i < Bb * Tt) out[i] = mask[i] ? 1.0f : 0.0f;
}

extern "C" void kernel_launch(void* const* d_in, const int* in_sizes, int n_in,
                              void* d_out, int out_size, void* d_ws, size_t ws_size,
                              hipStream_t stream) {
    const float* x  = (const float*)d_in[0];
    const int* mask = (const int*)d_in[1];
    const float* Wq = (const float*)d_in[2];
    const float* bq = (const float*)d_in[3];
    const float* Wk = (const float*)d_in[4];
    const float* bk = (const float*)d_in[5];
    const float* Wv = (const float*)d_in[6];
    const float* bv = (const float*)d_in[7];
    const float* Wp = (const float*)d_in[8];
    const float* bp = (const float*)d_in[9];
    float* out = (float*)d_out;

    size_t sz = (size_t)Bb * Tt * Cc;  // elements per activation buffer
    size_t wsz = (size_t)Cc * Cc;      // elements per weight matrix
    u16* xT = (u16*)d_ws;
    u16* qb = xT + sz;
    u16* kb = qb + sz;
    u16* vT = kb + sz;
    u16* wq16 = vT + sz;
    u16* wk16 = wq16 + wsz;
    u16* wv16 = wk16 + wsz;
    u16* wp16 = wv16 + wsz;
    u16* ob = xT;  // reuse xT: last read by V gemm, attn writes after (stream-ordered)

    int cvb = (int)(wsz / 4 / 256);  // 1024 blocks per weight
    cvt_bf16<<<cvb, 256, 0, stream>>>(Wq, wq16, (int)wsz);
    cvt_bf16<<<cvb, 256, 0, stream>>>(Wk, wk16, (int)wsz);
    cvt_bf16<<<cvb, 256, 0, stream>>>(Wv, wv16, (int)wsz);
    cvt_bf16<<<cvb, 256, 0, stream>>>(Wp, wp16, (int)wsz);
    transpose_x<<<dim3(Tt / 32, Cc / 32, Bb), dim3(32, 8), 0, stream>>>(x, xT);
    gemm_bt<<<dim3(Cc / 64, Tt / 64, Bb), 256, 0, stream>>>(xT, wq16, bq, nullptr, qb, 0);
    gemm_bt<<<dim3(Cc / 64, Tt / 64, Bb), 256, 0, stream>>>(xT, wk16, bk, nullptr, kb, 1);
    gemm_bt<<<dim3(Cc / 64, Tt / 64, Bb), 256, 0, stream>>>(xT, wv16, bv, nullptr, vT, 2);
    attn<<<dim3(Tt / 64, Bb * Hh), 256, 0, stream>>>(qb, kb, vT, mask, ob);
    gemm_bt<<<dim3(Cc / 64, Tt / 64, Bb), 256, 0, stream>>>(ob, wp16, bp, mask, out, 3);
    if (out_size >= Bb * Cc * Tt + Bb * Tt)
        mask_out_k<<<dim3((Bb * Tt + 255) / 256), 256, 0, stream>>>(
            mask, out + (size_t)Bb * Cc * Tt);
}